// Round 6
// baseline (357.319 us; speedup 1.0000x reference)
//
#include <hip/hip_runtime.h>
#include <hip/hip_bf16.h>
#include <math.h>

// x: (2, 192, 256, 256) f32 ; w_qkv: (192, 576) ; b_qkv: (576,)
// windows: 32x32 = 1024 per batch, 8x8=64 pixels each
// out: (2, 1024, 4, 64, 192) f32
#define NB   2
#define NC   192
#define HW   256
#define NWIN 1024
#define SHW  64
#define NDQ  192
#define WCOL 576

typedef short bf16x8 __attribute__((ext_vector_type(8)));
typedef float f32x4  __attribute__((ext_vector_type(4)));

__device__ inline unsigned int bf16pack(float a, float b) {
  unsigned int ua = __builtin_bit_cast(unsigned int, a);
  ua += 0x7fffu + ((ua >> 16) & 1u);
  unsigned int ub = __builtin_bit_cast(unsigned int, b);
  ub += 0x7fffu + ((ub >> 16) & 1u);
  return (ua >> 16) | (ub & 0xffff0000u);
}

// ---------------- K0: precompute WvT bf16 [d][c] ----------------
__global__ __launch_bounds__(256) void k0_wvt(const float* __restrict__ w,
                                              unsigned short* __restrict__ wvt) {
  int id = blockIdx.x * 256 + threadIdx.x;   // 192*192 = 36864
  int d = id / NC, c = id - d * NC;
  unsigned int u = __builtin_bit_cast(unsigned int, w[c * WCOL + 2 * NDQ + d]);
  u += 0x7fffu + ((u >> 16) & 1u);
  wvt[d * NC + c] = (unsigned short)(u >> 16);
}

// ---------------- K1: window mean of x -> xmean[b][n][c] ----------------
__global__ __launch_bounds__(256) void k1_mean(const float* __restrict__ x,
                                               float* __restrict__ xmean) {
  int id = blockIdx.x * 256 + threadIdx.x;
  int n  = id & 1023;
  int c  = (id >> 10) % NC;
  int b  = id / (NC * NWIN);
  int wh = n >> 5, ww = n & 31;
  const float* p = x + (((size_t)(b * NC + c) * HW + wh * 8) * HW + ww * 8);
  double s = 0.0;
#pragma unroll
  for (int r = 0; r < 8; ++r) {
    float4 a = *(const float4*)(p + r * HW);
    float4 q = *(const float4*)(p + r * HW + 4);
    s += (double)a.x + a.y + a.z + a.w + q.x + q.y + q.z + q.w;
  }
  xmean[(size_t)(b * NWIN + n) * NC + c] = (float)(s * (1.0 / 64.0));
}

// ---------------- K2: q_win (scaled) and k_win^T ----------------
__global__ __launch_bounds__(192) void k2_qk(const float* __restrict__ xmean,
                                             const float* __restrict__ w,
                                             const float* __restrict__ bias,
                                             float* __restrict__ qw,
                                             float* __restrict__ kwT) {
  int b = blockIdx.y, n = blockIdx.x;
  int d = threadIdx.x;
  __shared__ float xs[NC];
  xs[d] = xmean[(size_t)(b * NWIN + n) * NC + d];
  __syncthreads();
  double aq = 0.0, ak = 0.0;
  for (int c = 0; c < NC; ++c) {
    double xc = (double)xs[c];
    aq += xc * (double)w[c * WCOL + d];
    ak += xc * (double)w[c * WCOL + NDQ + d];
  }
  const float scale = 0.0721687836487032f;
  float qv = (float)aq + bias[d];
  float kv = (float)ak + bias[NDQ + d];
  qw[(size_t)(b * NWIN + n) * NC + d] = qv * scale;
  kwT[(size_t)b * NC * NWIN + (size_t)d * NWIN + n] = kv;
}

// ---------------- K3: 8 logit rows per block (512 thr), per-wave top-4 ----------------
__global__ __launch_bounds__(512) void k3_topk(const float* __restrict__ qw,
                                               const float* __restrict__ kwT,
                                               int* __restrict__ topk) {
  int b = blockIdx.y, n0 = blockIdx.x * 8;
  int t = threadIdx.x;
  __shared__ float qs[8][NC];
  __shared__ float lg[8][NWIN];
#pragma unroll
  for (int i = 0; i < 3; ++i) {
    int l = i * 512 + t;
    int r = l / NC, c = l - r * NC;
    qs[r][c] = qw[(size_t)(b * NWIN + n0 + r) * NC + c];
  }
  __syncthreads();

  double acc[8][2];
#pragma unroll
  for (int r = 0; r < 8; ++r) { acc[r][0] = 0.0; acc[r][1] = 0.0; }

  const float* kb = kwT + (size_t)b * NC * NWIN;
#pragma unroll 2
  for (int c = 0; c < NC; ++c) {
    float2 kv = *(const float2*)(kb + (size_t)c * NWIN + t * 2);
    double k0 = (double)kv.x, k1 = (double)kv.y;
#pragma unroll
    for (int r = 0; r < 8; ++r) {
      double q = (double)qs[r][c];
      acc[r][0] += q * k0;
      acc[r][1] += q * k1;
    }
  }
#pragma unroll
  for (int r = 0; r < 8; ++r) {
    lg[r][t * 2]     = (float)acc[r][0];
    lg[r][t * 2 + 1] = (float)acc[r][1];
  }
  __syncthreads();

  int wave = t >> 6, lane = t & 63;
  int r = wave;  // 8 waves, one row each
  float v4[4];
  int   i4[4];
#pragma unroll
  for (int j = 0; j < 4; ++j) { v4[j] = -INFINITY; i4[j] = 0x7fffffff; }
  for (int i = 0; i < 16; ++i) {
    int idx = i * 64 + lane;
    float v = lg[r][idx];
    if (v > v4[3] || (v == v4[3] && idx < i4[3])) {
      v4[3] = v; i4[3] = idx;
#pragma unroll
      for (int j = 3; j > 0; --j) {
        if (v4[j] > v4[j-1] || (v4[j] == v4[j-1] && i4[j] < i4[j-1])) {
          float tv = v4[j]; v4[j] = v4[j-1]; v4[j-1] = tv;
          int ti = i4[j]; i4[j] = i4[j-1]; i4[j-1] = ti;
        }
      }
    }
  }
  for (int m = 1; m < 64; m <<= 1) {
    float ov[4]; int oi[4];
#pragma unroll
    for (int j = 0; j < 4; ++j) { ov[j] = __shfl_xor(v4[j], m); oi[j] = __shfl_xor(i4[j], m); }
    float nv[4]; int ni[4];
    int ia = 0, ib = 0;
#pragma unroll
    for (int j = 0; j < 4; ++j) {
      bool ta = (v4[ia] > ov[ib]) || (v4[ia] == ov[ib] && i4[ia] < oi[ib]);
      if (ta) { nv[j] = v4[ia]; ni[j] = i4[ia]; ++ia; }
      else    { nv[j] = ov[ib]; ni[j] = oi[ib]; ++ib; }
    }
#pragma unroll
    for (int j = 0; j < 4; ++j) { v4[j] = nv[j]; i4[j] = ni[j]; }
  }
  if (lane == 0) {
    int n = n0 + r;
#pragma unroll
    for (int k = 0; k < 4; ++k)
      topk[(size_t)(b * NWIN + n) * 4 + k] = i4[k];
  }
}

// ---------------- KC: one block per output slot — recompute V tile, write out ----------------
// 256 threads = 4 waves, wave = d-quarter (48 dims). x window staged in LDS bf16,
// layout [p(64)][c(192)] (384B rows = 3x128B stripes), 16B-slot XOR swizzle ^((p&7)<<4).
__global__ __launch_bounds__(256) void kC_slot(const float* __restrict__ x,
                                               const unsigned short* __restrict__ wvt,
                                               const float* __restrict__ bias,
                                               const int* __restrict__ topk,
                                               float* __restrict__ out) {
  int id = blockIdx.x;            // 8192 = b*4096 + n*4 + k
  int b = id >> 12;
  int m = topk[id];
  int wh = m >> 5, ww = m & 31;
  int t = threadIdx.x;

  __shared__ unsigned short Xs[12288];  // 24 KB

  // ---- stage x window -> LDS bf16 (channel pairs packed per dword) ----
  const float* xb = x + (size_t)(b * NC) * (HW * HW) + (size_t)(wh * 8) * HW + ww * 8;
#pragma unroll
  for (int i = 0; i < 6; ++i) {
    int u = i * 256 + t;        // 1536 units: 96 ch-pairs x 8 rows x 2 col4
    int cp = u >> 4;            // 0..95
    int q  = u & 15;
    int rw = q >> 1, c4 = q & 1;
    const float* pl = xb + (size_t)(2 * cp) * (HW * HW) + rw * HW + c4 * 4;
    float4 va = *(const float4*)pl;
    float4 vb = *(const float4*)(pl + HW * HW);
    float fa[4] = {va.x, va.y, va.z, va.w};
    float fb[4] = {vb.x, vb.y, vb.z, vb.w};
#pragma unroll
    for (int k = 0; k < 4; ++k) {
      int p = rw * 8 + c4 * 4 + k;
      unsigned int pk = bf16pack(fa[k], fb[k]);
      *(unsigned int*)((char*)Xs + (p * 384 + ((cp * 4) ^ ((p & 7) << 4)))) = pk;
    }
  }

  int L = t & 63, dq = t >> 6;      // wave = d-quarter
  int col = L & 15, kg = L >> 4;

  f32x4 acc[4][3];
#pragma unroll
  for (int dt = 0; dt < 3; ++dt) {
    float bv = bias[2 * NDQ + dq * 48 + dt * 16 + col];
    f32x4 bi = {bv, bv, bv, bv};
#pragma unroll
    for (int pt = 0; pt < 4; ++pt) acc[pt][dt] = bi;
  }

  __syncthreads();

#pragma unroll
  for (int cc = 0; cc < 6; ++cc) {
    bf16x8 Bf[3];
#pragma unroll
    for (int dt = 0; dt < 3; ++dt)
      Bf[dt] = *(const bf16x8*)(wvt + (size_t)(dq * 48 + dt * 16 + col) * NC + cc * 32 + kg * 8);

#pragma unroll
    for (int pt = 0; pt < 4; ++pt) {
      int p = pt * 16 + col;
      bf16x8 Af = *(const bf16x8*)((const char*)Xs +
                    (p * 384 + ((cc * 64 + kg * 16) ^ ((p & 7) << 4))));
      acc[pt][0] = __builtin_amdgcn_mfma_f32_16x16x32_bf16(Af, Bf[0], acc[pt][0], 0, 0, 0);
      acc[pt][1] = __builtin_amdgcn_mfma_f32_16x16x32_bf16(Af, Bf[1], acc[pt][1], 0, 0, 0);
      acc[pt][2] = __builtin_amdgcn_mfma_f32_16x16x32_bf16(Af, Bf[2], acc[pt][2], 0, 0, 0);
    }
  }

  // ---- write: D layout col=lane&15, row=(lane>>4)*4+reg ----
  float* dst = out + (size_t)id * (SHW * NC) + dq * 48 + col;
#pragma unroll
  for (int pt = 0; pt < 4; ++pt) {
#pragma unroll
    for (int rr = 0; rr < 4; ++rr) {
      float* dp = dst + (size_t)(pt * 16 + kg * 4 + rr) * NC;
      dp[0]  = acc[pt][0][rr];
      dp[16] = acc[pt][1][rr];
      dp[32] = acc[pt][2][rr];
    }
  }
}

extern "C" void kernel_launch(void* const* d_in, const int* in_sizes, int n_in,
                              void* d_out, int out_size, void* d_ws, size_t ws_size,
                              hipStream_t stream) {
  const float* x    = (const float*)d_in[0];
  const float* w    = (const float*)d_in[1];
  const float* bias = (const float*)d_in[2];
  float* out = (float*)d_out;

  float* xmean = (float*)d_ws;                   // 2*1024*192
  float* qw    = xmean + 393216;
  float* kwT   = qw + 393216;
  int*   topk  = (int*)(kwT + 393216);           // 2*1024*4
  unsigned short* wvt = (unsigned short*)(topk + 8192);  // 192*192 bf16

  k0_wvt<<<144, 256, 0, stream>>>(w, wvt);
  k1_mean<<<1536, 256, 0, stream>>>(x, xmean);
  k2_qk<<<dim3(1024, 2), 192, 0, stream>>>(xmean, w, bias, qw, kwT);
  k3_topk<<<dim3(128, 2), 512, 0, stream>>>(qw, kwT, topk);
  kC_slot<<<8192, 256, 0, stream>>>(x, wvt, bias, topk, out);
}

// Round 7
// 253.161 us; speedup vs baseline: 1.4114x; 1.4114x over previous
//
#include <hip/hip_runtime.h>
#include <hip/hip_bf16.h>
#include <math.h>

// x: (2, 192, 256, 256) f32 ; w_qkv: (192, 576) ; b_qkv: (576,)
// windows: 32x32 = 1024 per batch, 8x8=64 pixels each
// out: (2, 1024, 4, 64, 192) f32
#define NB   2
#define NC   192
#define HW   256
#define NWIN 1024
#define SHW  64
#define NDQ  192
#define WCOL 576

typedef short bf16x8 __attribute__((ext_vector_type(8)));
typedef float f32x4  __attribute__((ext_vector_type(4)));

__device__ inline unsigned int bf16pack(float a, float b) {
  unsigned int ua = __builtin_bit_cast(unsigned int, a);
  ua += 0x7fffu + ((ua >> 16) & 1u);
  unsigned int ub = __builtin_bit_cast(unsigned int, b);
  ub += 0x7fffu + ((ub >> 16) & 1u);
  return (ua >> 16) | (ub & 0xffff0000u);
}

__device__ inline unsigned short bf16r(float a) {
  unsigned int ua = __builtin_bit_cast(unsigned int, a);
  ua += 0x7fffu + ((ua >> 16) & 1u);
  return (unsigned short)(ua >> 16);
}

// ---------------- K0: precompute WvT bf16 [d][c] ----------------
__global__ __launch_bounds__(256) void k0_wvt(const float* __restrict__ w,
                                              unsigned short* __restrict__ wvt) {
  int id = blockIdx.x * 256 + threadIdx.x;   // 192*192 = 36864
  int d = id / NC, c = id - d * NC;
  wvt[d * NC + c] = bf16r(w[c * WCOL + 2 * NDQ + d]);
}

// ---------------- K1: window mean of x -> xmean[b][n][c] ----------------
__global__ __launch_bounds__(256) void k1_mean(const float* __restrict__ x,
                                               float* __restrict__ xmean) {
  int id = blockIdx.x * 256 + threadIdx.x;
  int n  = id & 1023;
  int c  = (id >> 10) % NC;
  int b  = id / (NC * NWIN);
  int wh = n >> 5, ww = n & 31;
  const float* p = x + (((size_t)(b * NC + c) * HW + wh * 8) * HW + ww * 8);
  double s = 0.0;
#pragma unroll
  for (int r = 0; r < 8; ++r) {
    float4 a = *(const float4*)(p + r * HW);
    float4 q = *(const float4*)(p + r * HW + 4);
    s += (double)a.x + a.y + a.z + a.w + q.x + q.y + q.z + q.w;
  }
  xmean[(size_t)(b * NWIN + n) * NC + c] = (float)(s * (1.0 / 64.0));
}

// ---------------- K2: q_win (scaled) and k_win^T ----------------
__global__ __launch_bounds__(192) void k2_qk(const float* __restrict__ xmean,
                                             const float* __restrict__ w,
                                             const float* __restrict__ bias,
                                             float* __restrict__ qw,
                                             float* __restrict__ kwT) {
  int b = blockIdx.y, n = blockIdx.x;
  int d = threadIdx.x;
  __shared__ float xs[NC];
  xs[d] = xmean[(size_t)(b * NWIN + n) * NC + d];
  __syncthreads();
  double aq = 0.0, ak = 0.0;
  for (int c = 0; c < NC; ++c) {
    double xc = (double)xs[c];
    aq += xc * (double)w[c * WCOL + d];
    ak += xc * (double)w[c * WCOL + NDQ + d];
  }
  const float scale = 0.0721687836487032f;
  float qv = (float)aq + bias[d];
  float kv = (float)ak + bias[NDQ + d];
  qw[(size_t)(b * NWIN + n) * NC + d] = qv * scale;
  kwT[(size_t)b * NC * NWIN + (size_t)d * NWIN + n] = kv;
}

// ---------------- K3: 8 logit rows per block (512 thr), per-wave top-4 ----------------
__global__ __launch_bounds__(512) void k3_topk(const float* __restrict__ qw,
                                               const float* __restrict__ kwT,
                                               int* __restrict__ topk) {
  int b = blockIdx.y, n0 = blockIdx.x * 8;
  int t = threadIdx.x;
  __shared__ float qs[8][NC];
  __shared__ float lg[8][NWIN];
#pragma unroll
  for (int i = 0; i < 3; ++i) {
    int l = i * 512 + t;
    int r = l / NC, c = l - r * NC;
    qs[r][c] = qw[(size_t)(b * NWIN + n0 + r) * NC + c];
  }
  __syncthreads();

  double acc[8][2];
#pragma unroll
  for (int r = 0; r < 8; ++r) { acc[r][0] = 0.0; acc[r][1] = 0.0; }

  const float* kb = kwT + (size_t)b * NC * NWIN;
#pragma unroll 2
  for (int c = 0; c < NC; ++c) {
    float2 kv = *(const float2*)(kb + (size_t)c * NWIN + t * 2);
    double k0 = (double)kv.x, k1 = (double)kv.y;
#pragma unroll
    for (int r = 0; r < 8; ++r) {
      double q = (double)qs[r][c];
      acc[r][0] += q * k0;
      acc[r][1] += q * k1;
    }
  }
#pragma unroll
  for (int r = 0; r < 8; ++r) {
    lg[r][t * 2]     = (float)acc[r][0];
    lg[r][t * 2 + 1] = (float)acc[r][1];
  }
  __syncthreads();

  int wave = t >> 6, lane = t & 63;
  int r = wave;  // 8 waves, one row each
  float v4[4];
  int   i4[4];
#pragma unroll
  for (int j = 0; j < 4; ++j) { v4[j] = -INFINITY; i4[j] = 0x7fffffff; }
  for (int i = 0; i < 16; ++i) {
    int idx = i * 64 + lane;
    float v = lg[r][idx];
    if (v > v4[3] || (v == v4[3] && idx < i4[3])) {
      v4[3] = v; i4[3] = idx;
#pragma unroll
      for (int j = 3; j > 0; --j) {
        if (v4[j] > v4[j-1] || (v4[j] == v4[j-1] && i4[j] < i4[j-1])) {
          float tv = v4[j]; v4[j] = v4[j-1]; v4[j-1] = tv;
          int ti = i4[j]; i4[j] = i4[j-1]; i4[j-1] = ti;
        }
      }
    }
  }
  for (int m = 1; m < 64; m <<= 1) {
    float ov[4]; int oi[4];
#pragma unroll
    for (int j = 0; j < 4; ++j) { ov[j] = __shfl_xor(v4[j], m); oi[j] = __shfl_xor(i4[j], m); }
    float nv[4]; int ni[4];
    int ia = 0, ib = 0;
#pragma unroll
    for (int j = 0; j < 4; ++j) {
      bool ta = (v4[ia] > ov[ib]) || (v4[ia] == ov[ib] && i4[ia] < oi[ib]);
      if (ta) { nv[j] = v4[ia]; ni[j] = i4[ia]; ++ia; }
      else    { nv[j] = ov[ib]; ni[j] = oi[ib]; ++ib; }
    }
#pragma unroll
    for (int j = 0; j < 4; ++j) { v4[j] = nv[j]; i4[j] = ni[j]; }
  }
  if (lane == 0) {
    int n = n0 + r;
#pragma unroll
    for (int k = 0; k < 4; ++k)
      topk[(size_t)(b * NWIN + n) * 4 + k] = i4[k];
  }
}

// ---------------- KA: MFMA bf16 V-GEMM for ALL windows -> Vtmp bf16 (L3-resident) ----------------
// 1024 threads = 16 waves; wave wv: win = wv>>2, d-quarter dq = wv&3 (48 dims).
__global__ __launch_bounds__(1024) void kA_vgemm(const float* __restrict__ x,
                                                 const unsigned short* __restrict__ wvt,
                                                 const float* __restrict__ bias,
                                                 unsigned short* __restrict__ vtmp) {
  int b = blockIdx.y, g = blockIdx.x;   // g in [0,256)
  int m0 = g * 4;
  int wh = m0 >> 5, ww0 = m0 & 31;
  int t = threadIdx.x;

  __shared__ unsigned short Xs[16384];  // 32 KB: 4 win * 64 p * 128B

  int L = t & 63, wv = t >> 6;
  int win = wv >> 2, dq = wv & 3;
  int col = L & 15, kg = L >> 4;

  f32x4 acc[4][3];
#pragma unroll
  for (int dt = 0; dt < 3; ++dt) {
    float bv = bias[2 * NDQ + dq * 48 + dt * 16 + col];
    f32x4 bi = {bv, bv, bv, bv};
#pragma unroll
    for (int pt = 0; pt < 4; ++pt) acc[pt][dt] = bi;
  }

  int cp = t & 15, gi = t >> 4;
  int r = gi >> 3, w4 = gi & 7;
  int winS = w4 >> 1;
  int pS = r * 8 + (w4 & 1) * 4;
  const float* xb = x + (size_t)(b * NC) * (HW * HW) + (size_t)(wh * 8 + r) * HW + ww0 * 8 + w4 * 4;

  for (int cc = 0; cc < 6; ++cc) {
    const float* pl = xb + (size_t)(cc * 32 + cp * 2) * (HW * HW);
    float4 va = *(const float4*)pl;
    float4 vb = *(const float4*)(pl + HW * HW);
    float fa[4] = {va.x, va.y, va.z, va.w};
    float fb[4] = {vb.x, vb.y, vb.z, vb.w};
#pragma unroll
    for (int i = 0; i < 4; ++i) {
      int p = pS + i;
      unsigned int pk = bf16pack(fa[i], fb[i]);
      *(unsigned int*)((char*)Xs + (winS * 8192 + p * 128 + ((cp * 4) ^ ((p & 7) << 4)))) = pk;
    }
    __syncthreads();

    bf16x8 Bf[3];
#pragma unroll
    for (int dt = 0; dt < 3; ++dt)
      Bf[dt] = *(const bf16x8*)(wvt + (size_t)(dq * 48 + dt * 16 + col) * NC + cc * 32 + kg * 8);

#pragma unroll
    for (int pt = 0; pt < 4; ++pt) {
      int p = pt * 16 + col;
      bf16x8 Af = *(const bf16x8*)((const char*)Xs +
                    (win * 8192 + p * 128 + ((kg * 16) ^ ((p & 7) << 4))));
      acc[pt][0] = __builtin_amdgcn_mfma_f32_16x16x32_bf16(Af, Bf[0], acc[pt][0], 0, 0, 0);
      acc[pt][1] = __builtin_amdgcn_mfma_f32_16x16x32_bf16(Af, Bf[1], acc[pt][1], 0, 0, 0);
      acc[pt][2] = __builtin_amdgcn_mfma_f32_16x16x32_bf16(Af, Bf[2], acc[pt][2], 0, 0, 0);
    }
    __syncthreads();
  }

  // store V tile bf16: D layout col=lane&15, row=(lane>>4)*4+reg
  unsigned short* dst = vtmp + (size_t)(b * NWIN + m0 + win) * (SHW * NC) + dq * 48 + col;
#pragma unroll
  for (int pt = 0; pt < 4; ++pt) {
#pragma unroll
    for (int rr = 0; rr < 4; ++rr) {
      unsigned short* dp = dst + (size_t)(pt * 16 + kg * 4 + rr) * NC;
      dp[0]  = bf16r(acc[pt][0][rr]);
      dp[16] = bf16r(acc[pt][1][rr]);
      dp[32] = bf16r(acc[pt][2][rr]);
    }
  }
}

// ---------------- KB: gather+convert out[slot] = f32(Vtmp[b, topk[slot]]) ----------------
__global__ __launch_bounds__(256) void kB_gather(const unsigned short* __restrict__ vtmp,
                                                 const int* __restrict__ topk,
                                                 float* __restrict__ out) {
  int id = blockIdx.x;            // 8192 = b*4096 + n*4 + k
  int b = id >> 12;
  int m = topk[id];
  const unsigned short* src = vtmp + (size_t)(b * NWIN + m) * (SHW * NC);
  float* dst = out + (size_t)id * (SHW * NC);
  int t = threadIdx.x;
#pragma unroll
  for (int i = 0; i < 6; ++i) {
    int u = i * 256 + t;          // 1536 units of 8 bf16
    uint4 v = *(const uint4*)(src + u * 8);
    float4 a, c;
    a.x = __builtin_bit_cast(float, v.x << 16);
    a.y = __builtin_bit_cast(float, v.x & 0xffff0000u);
    a.z = __builtin_bit_cast(float, v.y << 16);
    a.w = __builtin_bit_cast(float, v.y & 0xffff0000u);
    c.x = __builtin_bit_cast(float, v.z << 16);
    c.y = __builtin_bit_cast(float, v.z & 0xffff0000u);
    c.z = __builtin_bit_cast(float, v.w << 16);
    c.w = __builtin_bit_cast(float, v.w & 0xffff0000u);
    *(float4*)(dst + u * 8)     = a;
    *(float4*)(dst + u * 8 + 4) = c;
  }
}

extern "C" void kernel_launch(void* const* d_in, const int* in_sizes, int n_in,
                              void* d_out, int out_size, void* d_ws, size_t ws_size,
                              hipStream_t stream) {
  const float* x    = (const float*)d_in[0];
  const float* w    = (const float*)d_in[1];
  const float* bias = (const float*)d_in[2];
  float* out = (float*)d_out;

  unsigned short* vtmp = (unsigned short*)d_ws;          // 2*1024*64*192 bf16 = 50 MB
  float* xmean = (float*)(vtmp + (size_t)25165824);      // 2*1024*192
  float* qw    = xmean + 393216;
  float* kwT   = qw + 393216;
  int*   topk  = (int*)(kwT + 393216);                   // 2*1024*4
  unsigned short* wvt = (unsigned short*)(topk + 8192);  // 192*192 bf16

  k0_wvt<<<144, 256, 0, stream>>>(w, wvt);
  k1_mean<<<1536, 256, 0, stream>>>(x, xmean);
  k2_qk<<<dim3(1024, 2), 192, 0, stream>>>(xmean, w, bias, qw, kwT);
  k3_topk<<<dim3(128, 2), 512, 0, stream>>>(qw, kwT, topk);
  kA_vgemm<<<dim3(256, 2), 1024, 0, stream>>>(x, wvt, bias, vtmp);
  kB_gather<<<8192, 256, 0, stream>>>(vtmp, topk, out);
}